// Round 1
// 1998.465 us; speedup vs baseline: 1.3723x; 1.3723x over previous
//
#include <hip/hip_runtime.h>
#include <hip/hip_bf16.h>

// SARDecoder round 9: MFMA conv. k_conv (fp32 VALU, 890us, MfmaUtil=0) replaced
// by k_convm: 9 tap-shifted accumulating bf16 MFMA GEMMs (16x16x32), M=8192
// positions x N=512 ch x K=4608. featTp = bf16 [b][y+1][x+1][c] with baked zero
// halo; wb = bf16 [t][a][c]. LDS c-stride padded 64->72 bf16 (144B) for
// conflict-free stride-144 ds_read_b128. Transients overlay later-packed
// regions; packers moved after conv. Step pipeline unchanged.

#define RNN   512
#define V1    111
#define STEPS 31
#define HWP   256
#define XS_F  9216   // 256 x 36 half-K stage
#define POOLF 9760

typedef unsigned short ushortT;
typedef unsigned int   uintT;
typedef __attribute__((ext_vector_type(8))) short bf16x8;   // 8 bf16 (4 VGPRs)
typedef __attribute__((ext_vector_type(4))) float f32x4;

__device__ __forceinline__ float blo(uintT u){ union { uintT i; float f; } v; v.i = u << 16; return v.f; }
__device__ __forceinline__ float bhi(uintT u){ union { uintT i; float f; } v; v.i = u & 0xffff0000u; return v.f; }
__device__ __forceinline__ ushortT f2b(float f){
  __hip_bfloat16 h = __float2bfloat16(f);
  union { __hip_bfloat16 b; ushortT s; } v; v.b = h; return v.s;
}
__device__ __forceinline__ uintT packbf(float lo, float hi){
  return (uintT)f2b(lo) | ((uintT)f2b(hi) << 16);
}
__device__ __forceinline__ float sigf(float x){ return 1.f/(1.f + __expf(-x)); }
__device__ __forceinline__ float tanh_f(float x){ float e = __expf(2.f*x); return 1.f - 2.f/(e+1.f); }

// ---------------- init: zero states (98304 f32: h0 x2, h1 x2, c0, c1) ----------------
__global__ __launch_bounds__(256) void k_init(float* __restrict__ p){
  p[blockIdx.x*256 + threadIdx.x] = 0.f;   // grid 384
}

// ---------------- featT: features fp32 [b][c][y][x] -> bf16 [b][yy0..9][xi0..33][c], zero halo ----------------
__global__ __launch_bounds__(256) void k_featT(const float* __restrict__ feat, uintT* __restrict__ fT){
  int idx = blockIdx.x*256 + threadIdx.x;   // 2,785,280 (grid 10880)
  int cp = idx & 255;
  int r  = idx >> 8;         // b*340 + yy*34 + xi
  int xi = r % 34;
  int q  = r / 34;
  int yy = q % 10;
  int b  = q / 10;
  float v0 = 0.f, v1 = 0.f;
  if (yy >= 1 && yy <= 8 && xi >= 1 && xi <= 32){
    size_t base = (((size_t)b*512 + 2*cp)*8 + (yy-1))*32 + (xi-1);
    v0 = feat[base];
    v1 = feat[base + 256];   // c+1 stride = 8*32
  }
  fT[idx] = packbf(v0, v1);
}

// ---------------- conv-weight transpose: Wf[a][c][t] -> wb[t][a][c] bf16 ----------------
__global__ __launch_bounds__(256) void k_tconv2(const float* __restrict__ Wf, uintT* __restrict__ wb){
  int idx = blockIdx.x*256 + threadIdx.x;  // 1,179,648 (grid 4608)
  int cp = idx & 255;
  int r  = idx >> 8;        // t*512 + a
  int a  = r & 511;
  int t  = r >> 9;
  float v0 = Wf[((size_t)a*512 + 2*cp)*9 + t];
  float v1 = Wf[((size_t)a*512 + 2*cp + 1)*9 + t];
  wb[idx] = packbf(v0, v1);
}

// ---------------- bf16 packers ----------------
__global__ __launch_bounds__(256) void k_wgate(const float* __restrict__ w0,
    const float* __restrict__ w1, const float* __restrict__ w2, uintT* __restrict__ o){
  int idx = blockIdx.x*256 + threadIdx.x;    // 1,572,864
  int m = idx >> 19, r = idx & 524287;
  const float* s = (m==0)? w0 : (m==1)? w1 : w2;
  float2 v = *(const float2*)(s + 2*(size_t)r);
  o[idx] = packbf(v.x, v.y);
}
__global__ __launch_bounds__(256) void k_woutb(const float* __restrict__ W, uintT* __restrict__ o){
  int idx = blockIdx.x*256 + threadIdx.x;    // 56,832
  float2 v = *(const float2*)(W + 2*(size_t)idx);
  o[idx] = packbf(v.x, v.y);
}
__global__ __launch_bounds__(256) void k_featb(const float* __restrict__ F, uintT* __restrict__ o){
  int idx = blockIdx.x*256 + threadIdx.x;    // 2,097,152
  float2 v = *(const float2*)(F + 2*(size_t)idx);
  o[idx] = packbf(v.x, v.y);
}
// WstT[u][ap] = pack(Wst[2ap][u], Wst[2ap+1][u])  (coalesced sp-GEMV layout)
__global__ __launch_bounds__(256) void k_wstT(const float* __restrict__ Wst, uintT* __restrict__ o){
  int idx = blockIdx.x*256 + threadIdx.x;    // 131,072
  int u = idx >> 8, ap = idx & 255;
  o[idx] = packbf(Wst[(size_t)(2*ap)*512 + u], Wst[(size_t)(2*ap+1)*512 + u]);
}

// ---------------- M0[j][g] = sum_k wih0[j][k] * Wemb[k][g] ----------------
__global__ __launch_bounds__(128) void k_m0(const float* __restrict__ wih0,
                                            const float* __restrict__ Wemb,
                                            float* __restrict__ M0){
  int j = blockIdx.x, g = threadIdx.x;
  if (g < V1){
    float acc = 0.f;
    const float* wr = wih0 + (size_t)j*512;
    for (int k=0;k<512;k++) acc += wr[k] * Wemb[(size_t)k*V1 + g];
    M0[(size_t)j*112 + g] = acc;
  }
}

// ---------------- MFMA conv: 256 wgs, wg=(M 64 pos)x(N 256 a), 4 waves of M64xN64 ----------------
__global__ __launch_bounds__(256) void k_convm(const ushortT* __restrict__ fT,
                                               const ushortT* __restrict__ wb,
                                               const float* __restrict__ bfv,
                                               ushortT* __restrict__ fpj)
{
  // c-stride padded 64 -> 72 shorts (144 B): stride-144 b128 reads spread
  // uniformly over 32 banks (unpadded 128B stride = 16-way conflict).
  __shared__ __align__(16) ushortT a_lds[136*72];   // 4 rows x 34 xi x 64c  (19,584 B)
  __shared__ __align__(16) ushortT b_lds[256*72];   // 256 a x 64 c          (36,864 B)
  const int tid = threadIdx.x;
  const int w   = tid >> 6;       // wave 0..3 -> a-subrange
  const int l   = tid & 63;
  const int kg  = l >> 4;         // k-group 0..3
  const int ln  = l & 15;
  const int bid = blockIdx.x;     // 256
  const int nh  = bid & 1;        // a-half
  const int mt  = bid >> 1;       // 0..127
  const int b   = mt >> 2;
  const int y0  = (mt & 3) * 2;   // output rows y0, y0+1
  const int a0  = nh * 256;

  f32x4 acc[4][4];
  #pragma unroll
  for (int nb=0; nb<4; nb++){
    float bv = bfv[a0 + w*64 + nb*16 + ln];   // bias per output channel (col = ln)
    #pragma unroll
    for (int mb=0; mb<4; mb++){
      acc[mb][nb][0]=bv; acc[mb][nb][1]=bv; acc[mb][nb][2]=bv; acc[mb][nb][3]=bv;
    }
  }

  // 136 staged positions (4 rows x 34 xi) are CONTIGUOUS in featTp
  const char* aSrc = (const char*)(fT + (((size_t)b*10 + y0)*34)*512);
  const char* wSrc = (const char*)wb;

  for (int c0 = 0; c0 < 512; c0 += 64){
    // ---- stage A chunk: 1088 uint4 (prev compute done at trailing barrier) ----
    {
      const char* s = aSrc + (size_t)c0*2;
      #pragma unroll
      for (int i=0;i<4;i++){
        int idx = tid + i*256;
        int pos = idx >> 3, q = idx & 7;
        uint4 v = *(const uint4*)(s + (size_t)pos*1024 + q*16);
        *(uint4*)((char*)a_lds + pos*144 + q*16) = v;
      }
      if (tid < 64){
        int idx = 1024 + tid;
        int pos = idx >> 3, q = idx & 7;
        uint4 v = *(const uint4*)(s + (size_t)pos*1024 + q*16);
        *(uint4*)((char*)a_lds + pos*144 + q*16) = v;
      }
    }
    #pragma unroll
    for (int t=0; t<9; t++){
      const int ky = t/3, kx = t - (t/3)*3;
      // ---- stage B tile: wb[t][a0..a0+255][c0..c0+63], 2048 uint4 ----
      {
        const char* s = wSrc + (((size_t)t*512 + a0)*512 + c0)*2;
        #pragma unroll
        for (int i=0;i<8;i++){
          int idx = tid + i*256;
          int ai = idx >> 3, q = idx & 7;
          uint4 v = *(const uint4*)(s + (size_t)ai*1024 + q*16);
          *(uint4*)((char*)b_lds + ai*144 + q*16) = v;
        }
      }
      __syncthreads();
      #pragma unroll
      for (int ks=0; ks<2; ks++){
        bf16x8 afr[4], bfr[4];
        #pragma unroll
        for (int mb=0; mb<4; mb++){
          // pos = mb*16+ln; input row = (pos>>5)+ky, xi = (pos&31)+kx (halo baked)
          int row = ((mb>>1) + ky)*34 + (mb&1)*16 + ln + kx;
          afr[mb] = *(const bf16x8*)((const char*)a_lds + row*144 + kg*16 + ks*64);
        }
        #pragma unroll
        for (int nb=0; nb<4; nb++){
          int ai = w*64 + nb*16 + ln;
          bfr[nb] = *(const bf16x8*)((const char*)b_lds + ai*144 + kg*16 + ks*64);
        }
        #pragma unroll
        for (int mb=0; mb<4; mb++)
          #pragma unroll
          for (int nb=0; nb<4; nb++)
            acc[mb][nb] = __builtin_amdgcn_mfma_f32_16x16x32_bf16(afr[mb], bfr[nb], acc[mb][nb], 0, 0, 0);
      }
      __syncthreads();
    }
  }

  // ---- write fpj[b][p][a]: D row=(l>>4)*4+reg (position), col=l&15 (channel) ----
  #pragma unroll
  for (int mb=0; mb<4; mb++){
    #pragma unroll
    for (int nb=0; nb<4; nb++){
      int a = a0 + w*64 + nb*16 + ln;
      #pragma unroll
      for (int r4=0; r4<4; r4++){
        int pos = mb*16 + kg*4 + r4;
        fpj[((size_t)b*HWP + (y0*32 + pos))*512 + a] = f2b(acc[mb][nb][r4]);
      }
    }
  }
}

// ---------------- stage half-K (256 k x 32 b) of [512][32] state into xs[k][36] ----------------
__device__ __forceinline__ void stage_half(float* __restrict__ xs,
                                           const float* __restrict__ srcT,
                                           int half, int tid){
  const float* s = srcT + half*8192;
  #pragma unroll
  for (int i=0;i<16;i++){
    int idx = tid + i*512;
    xs[(idx >> 5)*36 + (idx & 31)] = s[idx];
  }
}

// ---------------- bf16-weight GEMM quarter ----------------
__device__ __forceinline__ void gemm_half_b(float acc[4][4], const uintT* __restrict__ wb,
                                            const float* __restrict__ xs,
                                            int koff, int kq, int jq, int bq, int u0){
  const uintT* w0 = wb + ((size_t)(jq*512 + u0))*256 + ((koff + kq*16) >> 1);
  const float* xp = xs + (kq*16)*36 + bq*4;
  #pragma unroll
  for (int kk=0; kk<16; kk+=8){
    float xv[8][4];
    #pragma unroll
    for (int i=0;i<8;i++){
      float4 tv = *(const float4*)(xp + (kk+i)*36);
      xv[i][0]=tv.x; xv[i][1]=tv.y; xv[i][2]=tv.z; xv[i][3]=tv.w;
    }
    #pragma unroll
    for (int r=0;r<4;r++){
      uint4 wq = *(const uint4*)(w0 + (size_t)r*256 + (kk>>1));
      float wf[8] = {blo(wq.x),bhi(wq.x),blo(wq.y),bhi(wq.y),
                     blo(wq.z),bhi(wq.z),blo(wq.w),bhi(wq.w)};
      #pragma unroll
      for (int bb=0;bb<4;bb++){
        float s = 0.f;
        #pragma unroll
        for (int i=0;i<8;i++) s += wf[i]*xv[i][bb];
        acc[r][bb] += s;
      }
    }
  }
}

// ---------------- one pipeline stage: 128 A + 128 B + 32 att blocks ----------------
__global__ __launch_bounds__(512) void k_step(int L,
    const int* __restrict__ gt, const float* __restrict__ M0,
    const uintT* __restrict__ wgb,
    const float* __restrict__ bih0, const float* __restrict__ bhh0,
    const float* __restrict__ bih1, const float* __restrict__ bhh1,
    const ushortT* __restrict__ featb, const ushortT* __restrict__ fpj,
    const uintT* __restrict__ WstTb, const float* __restrict__ watt,
    const uintT* __restrict__ Woutb, const float* __restrict__ bout,
    float* __restrict__ st, float* __restrict__ out)
{
  __shared__ __align__(16) float pool[POOLF];
  const int tid = threadIdx.x, bid = blockIdx.x;
  float* h0p = st;               // 2 parities x [512][32]
  float* h1p = st + 32768;       // 2 parities x [512][32]
  float* c0T = st + 65536;
  float* c1T = st + 81920;

  if (bid < 256){
    float* xs   = pool;
    float* part = pool;          // overlay after GEMM
    float* gsum = pool + XS_F;
    const int kq = tid >> 5, jq = (tid >> 3) & 3, bq = tid & 7;

    if (bid < 128){
      // ======= role A: gates0(L) + cell0(L); reads h0(L-1), writes h0(L) =======
      const int t = L;
      if (t > STEPS-1) return;
      const int u0 = bid*4;
      const float* h0r = h0p + ((t+1)&1)*16384;
      float*       h0w = h0p + (t&1)*16384;
      const uintT* whh0b = wgb;

      float acc[4][4] = {{0.f}};
      stage_half(xs, h0r, 0, tid); __syncthreads();
      gemm_half_b(acc, whh0b, xs, 0,   kq, jq, bq, u0); __syncthreads();
      stage_half(xs, h0r, 1, tid); __syncthreads();
      gemm_half_b(acc, whh0b, xs, 256, kq, jq, bq, u0); __syncthreads();
      #pragma unroll
      for (int r=0;r<4;r++)
        #pragma unroll
        for (int bb=0;bb<4;bb++)
          part[(kq*16 + jq*4 + r)*33 + bq*4 + bb] = acc[r][bb];
      __syncthreads();
      {
        int jj = tid >> 5, b = tid & 31;
        float s = 0.f;
        #pragma unroll
        for (int k2=0;k2<16;k2++) s += part[(k2*16 + jj)*33 + b];
        int m = jj >> 2, ul = jj & 3;
        int j = m*512 + u0 + ul;
        s += bih0[j] + bhh0[j];
        if (t > 0) s += M0[(size_t)j*112 + gt[b*STEPS + t - 1]];
        gsum[jj*33 + b] = s;
      }
      __syncthreads();
      if (tid < 128){
        int ul = tid >> 5, b = tid & 31;
        float gi = gsum[(0*4+ul)*33 + b], gf = gsum[(1*4+ul)*33 + b];
        float gg = gsum[(2*4+ul)*33 + b], go = gsum[(3*4+ul)*33 + b];
        int idx = (u0+ul)*32 + b;
        float cn = sigf(gf)*c0T[idx] + sigf(gi)*tanh_f(gg);
        c0T[idx] = cn;
        h0w[idx] = sigf(go)*tanh_f(cn);
      }
    } else {
      // ======= role B: gates1(s)+cell1(s), s=L-1; reads h0(s), h1(s-1); writes h1(s) =======
      const int s = L - 1;
      if (s < 0 || s > STEPS-1) return;
      const int u0 = (bid-128)*4;
      const float* h0c = h0p + (s&1)*16384;
      const float* h1r = h1p + ((s+1)&1)*16384;
      float*       h1w = h1p + (s&1)*16384;
      const uintT* wih1b = wgb + 524288;
      const uintT* whh1b = wgb + 1048576;

      float acc[4][4] = {{0.f}};
      stage_half(xs, h0c, 0, tid); __syncthreads();
      gemm_half_b(acc, wih1b, xs, 0,   kq, jq, bq, u0); __syncthreads();
      stage_half(xs, h0c, 1, tid); __syncthreads();
      gemm_half_b(acc, wih1b, xs, 256, kq, jq, bq, u0); __syncthreads();
      stage_half(xs, h1r, 0, tid); __syncthreads();
      gemm_half_b(acc, whh1b, xs, 0,   kq, jq, bq, u0); __syncthreads();
      stage_half(xs, h1r, 1, tid); __syncthreads();
      gemm_half_b(acc, whh1b, xs, 256, kq, jq, bq, u0); __syncthreads();
      #pragma unroll
      for (int r=0;r<4;r++)
        #pragma unroll
        for (int bb=0;bb<4;bb++)
          part[(kq*16 + jq*4 + r)*33 + bq*4 + bb] = acc[r][bb];
      __syncthreads();
      {
        int jj = tid >> 5, b = tid & 31;
        float s2 = 0.f;
        #pragma unroll
        for (int k2=0;k2<16;k2++) s2 += part[(k2*16 + jj)*33 + b];
        int m = jj >> 2, ul = jj & 3;
        int j = m*512 + u0 + ul;
        s2 += bih1[j] + bhh1[j];
        gsum[jj*33 + b] = s2;
      }
      __syncthreads();
      if (tid < 128){
        int ul = tid >> 5, b = tid & 31;
        float gi = gsum[(0*4+ul)*33 + b], gf = gsum[(1*4+ul)*33 + b];
        float gg = gsum[(2*4+ul)*33 + b], go = gsum[(3*4+ul)*33 + b];
        int idx = (u0+ul)*32 + b;
        float cn = sigf(gf)*c1T[idx] + sigf(gi)*tanh_f(gg);
        c1T[idx] = cn;
        h1w[idx] = sigf(go)*tanh_f(cn);
      }
    }
    return;
  }

  // ======= role C: attention(r), r=L-2; reads h1(r); self-computes sp =======
  const int r = L - 2;
  if (r < 0 || r > STEPS-1) return;
  const int b = bid - 256;
  float* h1s   = pool;
  float* spsl  = pool + 512;
  float* spA   = pool + 1024;
  float* spB   = pool + 1536;
  float* watts = pool + 2048;
  float* pals  = pool + 2560;
  float* attw  = pool + 3072;
  float* glim  = pool + 3328;
  float* red   = pool + 3840;

  const float* h1c = h1p + (r&1)*16384;
  h1s[tid]   = h1c[tid*32 + b];
  watts[tid] = watt[tid];
  __syncthreads();

  // sp[a] = sum_u WstT[u][a] * h1[u]; split u-range across tid>>8, coalesced loads
  {
    int ap = tid & 255, uh = tid >> 8;
    float s0 = 0.f, s1 = 0.f;
    const uintT* wp = WstTb + ((size_t)uh*256)*256 + ap;
    #pragma unroll 8
    for (int u=0; u<256; u++){
      uintT wv = wp[(size_t)u*256];
      float h = h1s[uh*256 + u];
      s0 += blo(wv)*h; s1 += bhi(wv)*h;
    }
    spA[tid] = s0; spB[tid] = s1;
  }
  __syncthreads();
  {
    int apx = tid >> 1, i = tid & 1;
    spsl[tid] = i ? (spB[apx] + spB[256+apx]) : (spA[apx] + spA[256+apx]);
  }
  __syncthreads();

  // attention logits over (p, a-half)
  {
    int p = tid & 255, ac = tid >> 8;
    const uint4* fr = (const uint4*)(fpj + ((size_t)b*HWP + p)*512 + ac*256);
    float al2 = 0.f;
    #pragma unroll 8
    for (int kb=0;kb<32;kb++){
      uint4 q = fr[kb];
      float v[8] = {blo(q.x),bhi(q.x),blo(q.y),bhi(q.y),blo(q.z),bhi(q.z),blo(q.w),bhi(q.w)};
      int a0 = ac*256 + kb*8;
      #pragma unroll
      for (int i=0;i<8;i++)
        al2 += watts[a0+i] * tanh_f(v[i] + spsl[a0+i]);
    }
    pals[tid] = al2;
  }
  __syncthreads();
  // softmax over 256 positions
  {
    float al2 = (tid < 256) ? (pals[tid] + pals[256+tid]) : -1e30f;
    float m = al2;
    #pragma unroll
    for (int off=32; off>0; off>>=1) m = fmaxf(m, __shfl_xor(m, off));
    if (tid < 256 && (tid & 63)==0) red[tid>>6] = m;
    __syncthreads();
    m = fmaxf(fmaxf(red[0],red[1]), fmaxf(red[2],red[3]));
    float e = (tid < 256) ? __expf(al2 - m) : 0.f;
    float s = e;
    #pragma unroll
    for (int off=32; off>0; off>>=1) s += __shfl_xor(s, off);
    __syncthreads();
    if (tid < 256 && (tid & 63)==0) red[tid>>6] = s;
    __syncthreads();
    if (tid < 256){
      float sa = red[0]+red[1]+red[2]+red[3];
      attw[tid] = e / sa;
    }
  }
  __syncthreads();
  // glimpse[c] = sum_p featb[b,c,p] * attw[p]
  {
    const uint4* fr = (const uint4*)(featb + ((size_t)b*512 + tid)*HWP);
    float acc = 0.f;
    #pragma unroll 8
    for (int kb=0;kb<32;kb++){
      uint4 q = fr[kb];
      const float* aw = attw + kb*8;
      acc += blo(q.x)*aw[0] + bhi(q.x)*aw[1] + blo(q.y)*aw[2] + bhi(q.y)*aw[3]
           + blo(q.z)*aw[4] + bhi(q.z)*aw[5] + blo(q.w)*aw[6] + bhi(q.w)*aw[7];
    }
    glim[tid] = acc;
  }
  __syncthreads();
  // logits = [h1, glimpse] @ Wout^T + b_out (bf16 weights)
  if (tid < V1){
    const uint4* wr = (const uint4*)(Woutb + (size_t)tid*512);
    float acc = bout[tid];
    #pragma unroll 8
    for (int kb=0;kb<64;kb++){
      uint4 q = wr[kb];
      const float* hx = h1s + kb*8;
      acc += blo(q.x)*hx[0] + bhi(q.x)*hx[1] + blo(q.y)*hx[2] + bhi(q.y)*hx[3]
           + blo(q.z)*hx[4] + bhi(q.z)*hx[5] + blo(q.w)*hx[6] + bhi(q.w)*hx[7];
    }
    #pragma unroll 8
    for (int kb=0;kb<64;kb++){
      uint4 q = wr[64+kb];
      const float* gx = glim + kb*8;
      acc += blo(q.x)*gx[0] + bhi(q.x)*gx[1] + blo(q.y)*gx[2] + bhi(q.y)*gx[3]
           + blo(q.z)*gx[4] + bhi(q.z)*gx[5] + blo(q.w)*gx[6] + bhi(q.w)*gx[7];
    }
    out[(size_t)b*STEPS*V1 + (size_t)r*V1 + tid] = acc;
  }
}

extern "C" void kernel_launch(void* const* d_in, const int* in_sizes, int n_in,
                              void* d_out, int out_size, void* d_ws, size_t ws_size,
                              hipStream_t stream)
{
  const float* features = (const float*)d_in[0];
  const int*   gt       = (const int*)d_in[2];
  const float* Wf    = (const float*)d_in[3];
  const float* bfv   = (const float*)d_in[4];
  const float* Wst   = (const float*)d_in[5];
  const float* watt  = (const float*)d_in[6];
  const float* Wemb  = (const float*)d_in[7];
  const float* wih0  = (const float*)d_in[8];
  const float* whh0  = (const float*)d_in[9];
  const float* bih0  = (const float*)d_in[10];
  const float* bhh0  = (const float*)d_in[11];
  const float* wih1  = (const float*)d_in[12];
  const float* whh1  = (const float*)d_in[13];
  const float* bih1  = (const float*)d_in[14];
  const float* bhh1  = (const float*)d_in[15];
  const float* Wout  = (const float*)d_in[16];
  const float* bout  = (const float*)d_in[17];
  float* out = (float*)d_out;

  // ---- workspace layout (bytes), total 25,133,056 (unchanged footprint) ----
  char* wsb = (char*)d_ws;
  ushortT* fpj   = (ushortT*)(wsb + 0);          //  8,388,608 persist
  ushortT* featb = (ushortT*)(wsb + 8388608);    //  8,388,608 persist (written after conv)
  float*   M0    = (float*)  (wsb + 16777216);   //    917,504
  uintT*   wgb   = (uintT*)  (wsb + 17694720);   //  6,291,456 (whh0|wih1|whh1 bf16)
  uintT*   Woutb = (uintT*)  (wsb + 23986176);   //    227,328 (pad to 229,376)
  uintT*   WstTb = (uintT*)  (wsb + 24215552);   //    524,288
  float*   st    = (float*)  (wsb + 24739840);   //    393,216 (h0 x2, h1 x2, c0, c1)
  // transients (dead after k_convm; overlay featb/M0/wgb/Woutb/WstTb region):
  uintT*   fTt   = (uintT*)  (wsb + 8388608);    // 11,141,120 bf16 featTp
  ushortT* wbt   = (ushortT*)(wsb + 19529728);   //  4,718,592 bf16 wb[t][a][c] (ends 24,248,320)

  k_init  <<<384,   256, 0, stream>>>(st);
  k_featT <<<10880, 256, 0, stream>>>(features, fTt);
  k_tconv2<<<4608,  256, 0, stream>>>(Wf, (uintT*)wbt);
  k_convm <<<256,   256, 0, stream>>>((const ushortT*)fTt, wbt, bfv, fpj);
  // packers run AFTER conv (their regions overlay the conv transients)
  k_wgate <<<6144,  256, 0, stream>>>(whh0, wih1, whh1, wgb);
  k_wstT  <<<512,   256, 0, stream>>>(Wst, WstTb);
  k_woutb <<<222,   256, 0, stream>>>(Wout, Woutb);
  k_m0    <<<2048,  128, 0, stream>>>(wih0, Wemb, M0);
  k_featb <<<8192,  256, 0, stream>>>(features, (uintT*)featb);

  for (int L = 0; L < STEPS + 2; L++){
    k_step<<<288, 512, 0, stream>>>(L, gt, M0, wgb, bih0, bhh0, bih1, bhh1,
                                    featb, fpj, WstTb, watt, Woutb, bout, st, out);
  }
  (void)in_sizes; (void)n_in; (void)out_size; (void)ws_size;
}

// Round 2
// 1834.175 us; speedup vs baseline: 1.4952x; 1.0896x over previous
//
#include <hip/hip_runtime.h>
#include <hip/hip_bf16.h>

// SARDecoder round 10: MFMA-ized recurrence. Roles A/B (LSTM gate GEMMs) move
// from 9-phase VALU-GEMV chains to 3/6-phase MFMA (16x16x32 bf16): h-states
// stored bf16 [b][k] (B-operand-ready); weights wgb already [j][k] bf16 rows
// (A-operand direct from global). K split across 8 waves, partials reduced in
// LDS. Biases+M0 folded (col 111 = bias-only for t=0). h1 dual-written (bf16
// for role B, f32 for unchanged role C). Conv kernel byte-identical to r9.

#define RNN   512
#define V1    111
#define STEPS 31
#define HWP   256
#define POOLF 11008

typedef unsigned short ushortT;
typedef unsigned int   uintT;
typedef __attribute__((ext_vector_type(8))) short bf16x8;   // 8 bf16 (4 VGPRs)
typedef __attribute__((ext_vector_type(4))) float f32x4;

__device__ __forceinline__ float blo(uintT u){ union { uintT i; float f; } v; v.i = u << 16; return v.f; }
__device__ __forceinline__ float bhi(uintT u){ union { uintT i; float f; } v; v.i = u & 0xffff0000u; return v.f; }
__device__ __forceinline__ ushortT f2b(float f){
  __hip_bfloat16 h = __float2bfloat16(f);
  union { __hip_bfloat16 b; ushortT s; } v; v.b = h; return v.s;
}
__device__ __forceinline__ uintT packbf(float lo, float hi){
  return (uintT)f2b(lo) | ((uintT)f2b(hi) << 16);
}
__device__ __forceinline__ bf16x8 u4_to_b8(uint4 u){
  union { uint4 a; bf16x8 b; } v; v.a = u; return v.b;
}
__device__ __forceinline__ float sigf(float x){ return 1.f/(1.f + __expf(-x)); }
__device__ __forceinline__ float tanh_f(float x){ float e = __expf(2.f*x); return 1.f - 2.f/(e+1.f); }

// ---------------- init: zero states (98304 f32 = 384 KB) ----------------
__global__ __launch_bounds__(256) void k_init(float* __restrict__ p){
  p[blockIdx.x*256 + threadIdx.x] = 0.f;   // grid 384
}

// ---------------- featT: features fp32 [b][c][y][x] -> bf16 [b][yy0..9][xi0..33][c], zero halo ----------------
__global__ __launch_bounds__(256) void k_featT(const float* __restrict__ feat, uintT* __restrict__ fT){
  int idx = blockIdx.x*256 + threadIdx.x;   // 2,785,280 (grid 10880)
  int cp = idx & 255;
  int r  = idx >> 8;         // b*340 + yy*34 + xi
  int xi = r % 34;
  int q  = r / 34;
  int yy = q % 10;
  int b  = q / 10;
  float v0 = 0.f, v1 = 0.f;
  if (yy >= 1 && yy <= 8 && xi >= 1 && xi <= 32){
    size_t base = (((size_t)b*512 + 2*cp)*8 + (yy-1))*32 + (xi-1);
    v0 = feat[base];
    v1 = feat[base + 256];   // c+1 stride = 8*32
  }
  fT[idx] = packbf(v0, v1);
}

// ---------------- conv-weight transpose: Wf[a][c][t] -> wb[t][a][c] bf16 ----------------
__global__ __launch_bounds__(256) void k_tconv2(const float* __restrict__ Wf, uintT* __restrict__ wb){
  int idx = blockIdx.x*256 + threadIdx.x;  // 1,179,648 (grid 4608)
  int cp = idx & 255;
  int r  = idx >> 8;        // t*512 + a
  int a  = r & 511;
  int t  = r >> 9;
  float v0 = Wf[((size_t)a*512 + 2*cp)*9 + t];
  float v1 = Wf[((size_t)a*512 + 2*cp + 1)*9 + t];
  wb[idx] = packbf(v0, v1);
}

// ---------------- bf16 packers ----------------
__global__ __launch_bounds__(256) void k_wgate(const float* __restrict__ w0,
    const float* __restrict__ w1, const float* __restrict__ w2, uintT* __restrict__ o){
  int idx = blockIdx.x*256 + threadIdx.x;    // 1,572,864
  int m = idx >> 19, r = idx & 524287;
  const float* s = (m==0)? w0 : (m==1)? w1 : w2;
  float2 v = *(const float2*)(s + 2*(size_t)r);
  o[idx] = packbf(v.x, v.y);
}
__global__ __launch_bounds__(256) void k_woutb(const float* __restrict__ W, uintT* __restrict__ o){
  int idx = blockIdx.x*256 + threadIdx.x;    // 56,832
  float2 v = *(const float2*)(W + 2*(size_t)idx);
  o[idx] = packbf(v.x, v.y);
}
__global__ __launch_bounds__(256) void k_featb(const float* __restrict__ F, uintT* __restrict__ o){
  int idx = blockIdx.x*256 + threadIdx.x;    // 2,097,152
  float2 v = *(const float2*)(F + 2*(size_t)idx);
  o[idx] = packbf(v.x, v.y);
}
// WstT[u][ap] = pack(Wst[2ap][u], Wst[2ap+1][u])  (coalesced sp-GEMV layout)
__global__ __launch_bounds__(256) void k_wstT(const float* __restrict__ Wst, uintT* __restrict__ o){
  int idx = blockIdx.x*256 + threadIdx.x;    // 131,072
  int u = idx >> 8, ap = idx & 255;
  o[idx] = packbf(Wst[(size_t)(2*ap)*512 + u], Wst[(size_t)(2*ap+1)*512 + u]);
}

// ---------------- M0[j][g] = sum_k wih0[j][k]*Wemb[k][g] + bih0[j]+bhh0[j]; col 111 = bias-only ----------------
__global__ __launch_bounds__(128) void k_m0(const float* __restrict__ wih0,
                                            const float* __restrict__ Wemb,
                                            const float* __restrict__ bih0,
                                            const float* __restrict__ bhh0,
                                            float* __restrict__ M0){
  int j = blockIdx.x, g = threadIdx.x;
  float bs = bih0[j] + bhh0[j];
  if (g < V1){
    float acc = 0.f;
    const float* wr = wih0 + (size_t)j*512;
    for (int k=0;k<512;k++) acc += wr[k] * Wemb[(size_t)k*V1 + g];
    M0[(size_t)j*112 + g] = acc + bs;
  } else if (g == V1){
    M0[(size_t)j*112 + V1] = bs;
  }
}

// ---------------- MFMA conv (unchanged from r9): 256 wgs, wg=(M 64 pos)x(N 256 a) ----------------
__global__ __launch_bounds__(256) void k_convm(const ushortT* __restrict__ fT,
                                               const ushortT* __restrict__ wb,
                                               const float* __restrict__ bfv,
                                               ushortT* __restrict__ fpj)
{
  __shared__ __align__(16) ushortT a_lds[136*72];   // 4 rows x 34 xi x 64c  (19,584 B)
  __shared__ __align__(16) ushortT b_lds[256*72];   // 256 a x 64 c          (36,864 B)
  const int tid = threadIdx.x;
  const int w   = tid >> 6;       // wave 0..3 -> a-subrange
  const int l   = tid & 63;
  const int kg  = l >> 4;         // k-group 0..3
  const int ln  = l & 15;
  const int bid = blockIdx.x;     // 256
  const int nh  = bid & 1;        // a-half
  const int mt  = bid >> 1;       // 0..127
  const int b   = mt >> 2;
  const int y0  = (mt & 3) * 2;   // output rows y0, y0+1
  const int a0  = nh * 256;

  f32x4 acc[4][4];
  #pragma unroll
  for (int nb=0; nb<4; nb++){
    float bv = bfv[a0 + w*64 + nb*16 + ln];
    #pragma unroll
    for (int mb=0; mb<4; mb++){
      acc[mb][nb][0]=bv; acc[mb][nb][1]=bv; acc[mb][nb][2]=bv; acc[mb][nb][3]=bv;
    }
  }

  const char* aSrc = (const char*)(fT + (((size_t)b*10 + y0)*34)*512);
  const char* wSrc = (const char*)wb;

  for (int c0 = 0; c0 < 512; c0 += 64){
    {
      const char* s = aSrc + (size_t)c0*2;
      #pragma unroll
      for (int i=0;i<4;i++){
        int idx = tid + i*256;
        int pos = idx >> 3, q = idx & 7;
        uint4 v = *(const uint4*)(s + (size_t)pos*1024 + q*16);
        *(uint4*)((char*)a_lds + pos*144 + q*16) = v;
      }
      if (tid < 64){
        int idx = 1024 + tid;
        int pos = idx >> 3, q = idx & 7;
        uint4 v = *(const uint4*)(s + (size_t)pos*1024 + q*16);
        *(uint4*)((char*)a_lds + pos*144 + q*16) = v;
      }
    }
    #pragma unroll
    for (int t=0; t<9; t++){
      const int ky = t/3, kx = t - (t/3)*3;
      {
        const char* s = wSrc + (((size_t)t*512 + a0)*512 + c0)*2;
        #pragma unroll
        for (int i=0;i<8;i++){
          int idx = tid + i*256;
          int ai = idx >> 3, q = idx & 7;
          uint4 v = *(const uint4*)(s + (size_t)ai*1024 + q*16);
          *(uint4*)((char*)b_lds + ai*144 + q*16) = v;
        }
      }
      __syncthreads();
      #pragma unroll
      for (int ks=0; ks<2; ks++){
        bf16x8 afr[4], bfr[4];
        #pragma unroll
        for (int mb=0; mb<4; mb++){
          int row = ((mb>>1) + ky)*34 + (mb&1)*16 + ln + kx;
          afr[mb] = *(const bf16x8*)((const char*)a_lds + row*144 + kg*16 + ks*64);
        }
        #pragma unroll
        for (int nb=0; nb<4; nb++){
          int ai = w*64 + nb*16 + ln;
          bfr[nb] = *(const bf16x8*)((const char*)b_lds + ai*144 + kg*16 + ks*64);
        }
        #pragma unroll
        for (int mb=0; mb<4; mb++)
          #pragma unroll
          for (int nb=0; nb<4; nb++)
            acc[mb][nb] = __builtin_amdgcn_mfma_f32_16x16x32_bf16(afr[mb], bfr[nb], acc[mb][nb], 0, 0, 0);
      }
      __syncthreads();
    }
  }

  #pragma unroll
  for (int mb=0; mb<4; mb++){
    #pragma unroll
    for (int nb=0; nb<4; nb++){
      int a = a0 + w*64 + nb*16 + ln;
      #pragma unroll
      for (int r4=0; r4<4; r4++){
        int pos = mb*16 + kg*4 + r4;
        fpj[((size_t)b*HWP + (y0*32 + pos))*512 + a] = f2b(acc[mb][nb][r4]);
      }
    }
  }
}

// ---------------- stage bf16 state [32 b][256 uints] global -> LDS [32][268] (padded) ----------------
__device__ __forceinline__ void stage_state(uintT* __restrict__ hs,
                                            const uintT* __restrict__ src, int tid){
  #pragma unroll
  for (int i=0;i<16;i++){
    int g = tid + i*512;
    int b = g >> 8, ku = g & 255;
    hs[b*268 + ku] = src[g];
  }
}

// ---------------- one pipeline stage: 64 A + 64 B + 32 att blocks (512 thr) ----------------
__global__ __launch_bounds__(512) void k_step(int L,
    const int* __restrict__ gt, const float* __restrict__ M0,
    const uintT* __restrict__ wgb,
    const float* __restrict__ bih1, const float* __restrict__ bhh1,
    const ushortT* __restrict__ featb, const ushortT* __restrict__ fpj,
    const uintT* __restrict__ WstTb, const float* __restrict__ watt,
    const uintT* __restrict__ Woutb, const float* __restrict__ bout,
    float* __restrict__ st, float* __restrict__ out)
{
  __shared__ __align__(16) float pool[POOLF];
  const int tid = threadIdx.x, bid = blockIdx.x;
  // state layout (st = 98304 floats = 384 KB):
  uintT* h0bf = (uintT*)st;            // 2 parities x [32 b][256 u] bf16
  uintT* h1bf = (uintT*)st + 16384;    // 2 parities x [32 b][256 u] bf16
  float* h1f  = st + 32768;            // 2 parities x [512 k][32 b] f32 (role C)
  float* c0T  = st + 65536;            // [512][32]
  float* c1T  = st + 81920;            // [512][32]

  if (bid < 128){
    // ======= roles A/B: MFMA gate GEMMs =======
    uintT* hs = (uintT*)pool;          // 8576 uints (34,304 B), row stride 268 u
    float* gs = pool + 8576;           // [2 ks2][32 row][33] partial D
    float* hv = pool + 10688;          // [8][33] new h staging for bf16 pack

    const int w   = tid >> 6;          // wave 0..7
    const int l   = tid & 63;
    const int kg  = l >> 4;            // k-octet / D-row group (= gate index)
    const int ln  = l & 15;            // A-row / D-col lane
    const int ks2 = w >> 2;            // K half
    const int rt  = (w >> 1) & 1;      // row-tile (unit group)
    const int nh  = w & 1;             // batch half
    const bool isA = bid < 64;
    const int u0 = (isA ? bid : bid - 64) * 8;
    const int t  = isA ? L : L - 1;    // time index of gates being computed
    if (t < 0 || t > STEPS-1) return;

    // A-frag row for this lane (verified convm convention: A row = ln)
    const int jrow = (ln >> 2)*512 + u0 + rt*4 + (ln & 3);
    const ushortT* hb = (const ushortT*)hs + (nh*16 + ln)*536 + kg*8;

    f32x4 acc = {0.f, 0.f, 0.f, 0.f};

    if (isA){
      // gates0(t) = whh0 @ h0(t-1) [+ M0-embed incl. biases in cell phase]
      stage_state(hs, h0bf + ((t+1)&1)*8192, tid);
      __syncthreads();
      const uintT* wp = wgb + (size_t)jrow*256 + kg*4;          // whh0
      #pragma unroll
      for (int s8=0; s8<8; s8++){
        int s = ks2*8 + s8;
        uint4 aw = *(const uint4*)(wp + s*16);
        bf16x8 bfr = *(const bf16x8*)(hb + s*32);
        acc = __builtin_amdgcn_mfma_f32_16x16x32_bf16(u4_to_b8(aw), bfr, acc, 0, 0, 0);
      }
    } else {
      // gates1(t) = wih1 @ h0(t) + whh1 @ h1(t-1)
      stage_state(hs, h0bf + (t&1)*8192, tid);
      __syncthreads();
      const uintT* wp1 = wgb + 524288 + (size_t)jrow*256 + kg*4;  // wih1
      #pragma unroll
      for (int s8=0; s8<8; s8++){
        int s = ks2*8 + s8;
        uint4 aw = *(const uint4*)(wp1 + s*16);
        bf16x8 bfr = *(const bf16x8*)(hb + s*32);
        acc = __builtin_amdgcn_mfma_f32_16x16x32_bf16(u4_to_b8(aw), bfr, acc, 0, 0, 0);
      }
      __syncthreads();
      stage_state(hs, h1bf + ((t+1)&1)*8192, tid);
      __syncthreads();
      const uintT* wp2 = wgb + 1048576 + (size_t)jrow*256 + kg*4; // whh1
      #pragma unroll
      for (int s8=0; s8<8; s8++){
        int s = ks2*8 + s8;
        uint4 aw = *(const uint4*)(wp2 + s*16);
        bf16x8 bfr = *(const bf16x8*)(hb + s*32);
        acc = __builtin_amdgcn_mfma_f32_16x16x32_bf16(u4_to_b8(aw), bfr, acc, 0, 0, 0);
      }
    }
    // D[kg*4+r][nh*16+ln]: gate kg, unit u0+rt*4+r, batch nh*16+ln
    #pragma unroll
    for (int r=0;r<4;r++)
      gs[(ks2*32 + kg*8 + rt*4 + r)*33 + nh*16 + ln] = acc[r];
    __syncthreads();

    if (tid < 256){
      const int ul = tid >> 5, b = tid & 31, u = u0 + ul;
      float g4[4];
      #pragma unroll
      for (int g=0; g<4; g++){
        float sacc = gs[(g*8+ul)*33 + b] + gs[(32 + g*8+ul)*33 + b];
        int j = g*512 + u;
        if (isA){
          int sym = (t > 0) ? gt[b*STEPS + t - 1] : V1;   // col 111 = bias-only
          sacc += M0[(size_t)j*112 + sym];
        } else {
          sacc += bih1[j] + bhh1[j];
        }
        g4[g] = sacc;
      }
      float* cT = isA ? c0T : c1T;
      int idx = u*32 + b;
      float cn = sigf(g4[1])*cT[idx] + sigf(g4[0])*tanh_f(g4[2]);
      cT[idx] = cn;
      float h = sigf(g4[3])*tanh_f(cn);
      if (!isA) h1f[(t&1)*16384 + idx] = h;               // f32 copy for role C
      hv[ul*33 + b] = h;
    }
    __syncthreads();
    if (tid < 128){
      const int up = tid >> 5, b = tid & 31;
      uintT* hw = (isA ? h0bf : h1bf) + (t&1)*8192;
      hw[b*256 + (u0>>1) + up] = packbf(hv[(up*2)*33 + b], hv[(up*2+1)*33 + b]);
    }
    return;
  }

  // ======= role C: attention(r), r=L-2 (unchanged from r9) =======
  const int r = L - 2;
  if (r < 0 || r > STEPS-1) return;
  const int b = bid - 128;
  float* h1s   = pool;
  float* spsl  = pool + 512;
  float* spA   = pool + 1024;
  float* spB   = pool + 1536;
  float* watts = pool + 2048;
  float* pals  = pool + 2560;
  float* attw  = pool + 3072;
  float* glim  = pool + 3328;
  float* red   = pool + 3840;

  const float* h1c = h1f + (r&1)*16384;
  h1s[tid]   = h1c[tid*32 + b];
  watts[tid] = watt[tid];
  __syncthreads();

  // sp[a] = sum_u WstT[u][a] * h1[u]
  {
    int ap = tid & 255, uh = tid >> 8;
    float s0 = 0.f, s1 = 0.f;
    const uintT* wp = WstTb + ((size_t)uh*256)*256 + ap;
    #pragma unroll 8
    for (int u=0; u<256; u++){
      uintT wv = wp[(size_t)u*256];
      float h = h1s[uh*256 + u];
      s0 += blo(wv)*h; s1 += bhi(wv)*h;
    }
    spA[tid] = s0; spB[tid] = s1;
  }
  __syncthreads();
  {
    int apx = tid >> 1, i = tid & 1;
    spsl[tid] = i ? (spB[apx] + spB[256+apx]) : (spA[apx] + spA[256+apx]);
  }
  __syncthreads();

  // attention logits over (p, a-half)
  {
    int p = tid & 255, ac = tid >> 8;
    const uint4* fr = (const uint4*)(fpj + ((size_t)b*HWP + p)*512 + ac*256);
    float al2 = 0.f;
    #pragma unroll 8
    for (int kb=0;kb<32;kb++){
      uint4 q = fr[kb];
      float v[8] = {blo(q.x),bhi(q.x),blo(q.y),bhi(q.y),blo(q.z),bhi(q.z),blo(q.w),bhi(q.w)};
      int a0 = ac*256 + kb*8;
      #pragma unroll
      for (int i=0;i<8;i++)
        al2 += watts[a0+i] * tanh_f(v[i] + spsl[a0+i]);
    }
    pals[tid] = al2;
  }
  __syncthreads();
  // softmax over 256 positions
  {
    float al2 = (tid < 256) ? (pals[tid] + pals[256+tid]) : -1e30f;
    float m = al2;
    #pragma unroll
    for (int off=32; off>0; off>>=1) m = fmaxf(m, __shfl_xor(m, off));
    if (tid < 256 && (tid & 63)==0) red[tid>>6] = m;
    __syncthreads();
    m = fmaxf(fmaxf(red[0],red[1]), fmaxf(red[2],red[3]));
    float e = (tid < 256) ? __expf(al2 - m) : 0.f;
    float s = e;
    #pragma unroll
    for (int off=32; off>0; off>>=1) s += __shfl_xor(s, off);
    __syncthreads();
    if (tid < 256 && (tid & 63)==0) red[tid>>6] = s;
    __syncthreads();
    if (tid < 256){
      float sa = red[0]+red[1]+red[2]+red[3];
      attw[tid] = e / sa;
    }
  }
  __syncthreads();
  // glimpse[c] = sum_p featb[b,c,p] * attw[p]
  {
    const uint4* fr = (const uint4*)(featb + ((size_t)b*512 + tid)*HWP);
    float acc = 0.f;
    #pragma unroll 8
    for (int kb=0;kb<32;kb++){
      uint4 q = fr[kb];
      const float* aw = attw + kb*8;
      acc += blo(q.x)*aw[0] + bhi(q.x)*aw[1] + blo(q.y)*aw[2] + bhi(q.y)*aw[3]
           + blo(q.z)*aw[4] + bhi(q.z)*aw[5] + blo(q.w)*aw[6] + bhi(q.w)*aw[7];
    }
    glim[tid] = acc;
  }
  __syncthreads();
  // logits = [h1, glimpse] @ Wout^T + b_out (bf16 weights)
  if (tid < V1){
    const uint4* wr = (const uint4*)(Woutb + (size_t)tid*512);
    float acc = bout[tid];
    #pragma unroll 8
    for (int kb=0;kb<64;kb++){
      uint4 q = wr[kb];
      const float* hx = h1s + kb*8;
      acc += blo(q.x)*hx[0] + bhi(q.x)*hx[1] + blo(q.y)*hx[2] + bhi(q.y)*hx[3]
           + blo(q.z)*hx[4] + bhi(q.z)*hx[5] + blo(q.w)*hx[6] + bhi(q.w)*hx[7];
    }
    #pragma unroll 8
    for (int kb=0;kb<64;kb++){
      uint4 q = wr[64+kb];
      const float* gx = glim + kb*8;
      acc += blo(q.x)*gx[0] + bhi(q.x)*gx[1] + blo(q.y)*gx[2] + bhi(q.y)*gx[3]
           + blo(q.z)*gx[4] + bhi(q.z)*gx[5] + blo(q.w)*gx[6] + bhi(q.w)*gx[7];
    }
    out[(size_t)b*STEPS*V1 + (size_t)r*V1 + tid] = acc;
  }
}

extern "C" void kernel_launch(void* const* d_in, const int* in_sizes, int n_in,
                              void* d_out, int out_size, void* d_ws, size_t ws_size,
                              hipStream_t stream)
{
  const float* features = (const float*)d_in[0];
  const int*   gt       = (const int*)d_in[2];
  const float* Wf    = (const float*)d_in[3];
  const float* bfv   = (const float*)d_in[4];
  const float* Wst   = (const float*)d_in[5];
  const float* watt  = (const float*)d_in[6];
  const float* Wemb  = (const float*)d_in[7];
  const float* wih0  = (const float*)d_in[8];
  const float* whh0  = (const float*)d_in[9];
  const float* bih0  = (const float*)d_in[10];
  const float* bhh0  = (const float*)d_in[11];
  const float* wih1  = (const float*)d_in[12];
  const float* whh1  = (const float*)d_in[13];
  const float* bih1  = (const float*)d_in[14];
  const float* bhh1  = (const float*)d_in[15];
  const float* Wout  = (const float*)d_in[16];
  const float* bout  = (const float*)d_in[17];
  float* out = (float*)d_out;

  // ---- workspace layout (bytes), total 25,133,056 (unchanged footprint) ----
  char* wsb = (char*)d_ws;
  ushortT* fpj   = (ushortT*)(wsb + 0);          //  8,388,608 persist
  ushortT* featb = (ushortT*)(wsb + 8388608);    //  8,388,608 persist (written after conv)
  float*   M0    = (float*)  (wsb + 16777216);   //    917,504 (incl. bias col 111)
  uintT*   wgb   = (uintT*)  (wsb + 17694720);   //  6,291,456 (whh0|wih1|whh1 bf16)
  uintT*   Woutb = (uintT*)  (wsb + 23986176);   //    227,328 (pad to 229,376)
  uintT*   WstTb = (uintT*)  (wsb + 24215552);   //    524,288
  float*   st    = (float*)  (wsb + 24739840);   //    393,216 (h0bf x2, h1bf x2, h1f x2, c0, c1)
  // transients (dead after k_convm; overlay featb/M0/wgb/Woutb/WstTb region):
  uintT*   fTt   = (uintT*)  (wsb + 8388608);    // 11,141,120 bf16 featTp
  ushortT* wbt   = (ushortT*)(wsb + 19529728);   //  4,718,592 bf16 wb[t][a][c] (ends 24,248,320)

  k_init  <<<384,   256, 0, stream>>>(st);
  k_featT <<<10880, 256, 0, stream>>>(features, fTt);
  k_tconv2<<<4608,  256, 0, stream>>>(Wf, (uintT*)wbt);
  k_convm <<<256,   256, 0, stream>>>((const ushortT*)fTt, wbt, bfv, fpj);
  // packers run AFTER conv (their regions overlay the conv transients)
  k_wgate <<<6144,  256, 0, stream>>>(whh0, wih1, whh1, wgb);
  k_wstT  <<<512,   256, 0, stream>>>(Wst, WstTb);
  k_woutb <<<222,   256, 0, stream>>>(Wout, Woutb);
  k_m0    <<<2048,  128, 0, stream>>>(wih0, Wemb, bih0, bhh0, M0);
  k_featb <<<8192,  256, 0, stream>>>(features, (uintT*)featb);

  for (int L = 0; L < STEPS + 2; L++){
    k_step<<<160, 512, 0, stream>>>(L, gt, M0, wgb, bih1, bhh1,
                                    featb, fpj, WstTb, watt, Woutb, bout, st, out);
  }
  (void)in_sizes; (void)n_in; (void)out_size; (void)ws_size;
}